// Round 15
// baseline (1108.022 us; speedup 1.0000x reference)
//
#include <hip/hip_runtime.h>
#include <hip/hip_cooperative_groups.h>

namespace cg = cooperative_groups;

#define N_NODES 20000
#define N_EDGES 200000
#define HID 128
#define STR 136   // LDS row stride in u16: 272B rows -> every b128 access 16B-aligned
#define NBLK 3125 // 64-edge tiles
#define GRID 768  // 3 blocks/CU required; launch_bounds(256,4) allows 4 -> margin

typedef unsigned short u16;
using bf16x8 = __attribute__((ext_vector_type(8))) __bf16;
using f32x4  = __attribute__((ext_vector_type(4))) float;

__device__ __forceinline__ u16 f2bf(float f) {
  union { float f; unsigned u; } v; v.f = f;
  unsigned u = v.u;
  return (u16)((u + 0x7FFFu + ((u >> 16) & 1u)) >> 16);
}
__device__ __forceinline__ float bf2f(unsigned s) {
  union { unsigned u; float f; } v; v.u = s << 16;
  return v.f;
}
__device__ __forceinline__ bf16x8 ld8(const u16* p) { return *(const bf16x8*)p; }

__device__ __forceinline__ void zero_acc(f32x4 acc[4][2]) {
#pragma unroll
  for (int i = 0; i < 4; ++i) {
    acc[i][0] = (f32x4){0.f, 0.f, 0.f, 0.f};
    acc[i][1] = (f32x4){0.f, 0.f, 0.f, 0.f};
  }
}

// r12-proven GEMM: wave owns 4 m-tiles x 2 n-tiles, depth-2 B ring.
template <int KSTEPS, typename AF>
__device__ __forceinline__ void wgemm(const u16* __restrict__ PW, AF afrag,
                                      f32x4 acc[4][2], int lane, int wave) {
  const u16* pb = PW + (wave * 2 * 64 + lane) * 8;
  bf16x8 b0[2], b1[2];
  b0[0] = ld8(pb);
  b1[0] = ld8(pb + 512);
#pragma unroll
  for (int ks = 0; ks < KSTEPS; ++ks) {
    const int cur = ks & 1, nxt = cur ^ 1;
    if (ks + 1 < KSTEPS) {
      b0[nxt] = ld8(pb + (ks + 1) * 4096);
      b1[nxt] = ld8(pb + (ks + 1) * 4096 + 512);
    }
#pragma unroll
    for (int mt = 0; mt < 4; ++mt) {
      bf16x8 a = afrag(ks, mt);
      acc[mt][0] = __builtin_amdgcn_mfma_f32_16x16x32_bf16(a, b0[cur], acc[mt][0], 0, 0, 0);
      acc[mt][1] = __builtin_amdgcn_mfma_f32_16x16x32_bf16(a, b1[cur], acc[mt][1], 0, 0, 0);
    }
  }
}

template <bool RELU>
__device__ __forceinline__ void epi_store(u16* buf, const f32x4 acc[4][2],
                                          const float* __restrict__ bias,
                                          int lane, int wave) {
  const int c = lane & 15, q = lane >> 4;
  const float bb0 = bias[wave * 32 + c], bb1 = bias[wave * 32 + 16 + c];
#pragma unroll
  for (int mt = 0; mt < 4; ++mt)
#pragma unroll
    for (int nt = 0; nt < 2; ++nt) {
      const float bb = nt ? bb1 : bb0;
      const int col = wave * 32 + nt * 16 + c;
#pragma unroll
      for (int r = 0; r < 4; ++r) {
        float v = acc[mt][nt][r] + bb;
        if (RELU) v = fmaxf(v, 0.f);
        buf[(mt * 16 + q * 4 + r) * STR + col] = f2bf(v);
      }
    }
}

__device__ __forceinline__ void flush_buf(const u16* buf, u16* __restrict__ gout,
                                          int e0, int tid) {
#pragma unroll
  for (int it = 0; it < 4; ++it) {
    int cid = tid + it * 256, e = cid >> 4, p = cid & 15;
    uint4 v = *(const uint4*)(buf + e * STR + p * 8);
    *(uint4*)(gout + (size_t)(e0 + e) * HID + p * 8) = v;
  }
}

__device__ __forceinline__ void stage_gather(const int* __restrict__ rowI,
                                             const int* __restrict__ colI,
                                             const u16* __restrict__ htab,
                                             u16* B0, u16* B1,
                                             int e0, int lane, int wave) {
  const int r = lane >> 4, p = lane & 15;
#pragma unroll
  for (int it = 0; it < 8; ++it) {
    int j = wave * 32 + it * 4 + r;  // 0..127
    int e = j & 63;
    int id = (j < 64) ? rowI[e0 + e] : colI[e0 + e];
    uint4 v = *(const uint4*)(htab + (size_t)id * HID + p * 8);
    *(uint4*)(((j < 64) ? B0 : B1) + e * STR + p * 8) = v;
  }
}

// ---------------- shared device bodies (used by mega + fallback) -------------

__device__ __forceinline__ void gnn1_tile(
    int e0, int tid, int lane, int wave, u16* B0, u16* B1,
    const int* rowI, const int* colI, const float* eattr, const u16* h2,
    const u16* pW1, const u16* pW2, const u16* pW3, const u16* pW4,
    const float* b1, const float* b2, const float* b3, const float* b4,
    u16* ea1, u16* h3) {
  const int m = lane & 15, q = lane >> 4;
  const int aoff = m * STR + q * 8;
  stage_gather(rowI, colI, h2, B0, B1, e0, lane, wave);

  bf16x8 ef[4];
#pragma unroll
  for (int mt = 0; mt < 4; ++mt) {
    union { u16 s[8]; uint4 u; bf16x8 v; } tt;
    tt.u = make_uint4(0u, 0u, 0u, 0u);
    if (q == 0) {
      float4 av = *(const float4*)(eattr + (size_t)(e0 + mt * 16 + m) * 4);
      tt.s[0] = f2bf(av.x); tt.s[1] = f2bf(av.y); tt.s[2] = f2bf(av.z); tt.s[3] = f2bf(av.w);
    }
    ef[mt] = tt.v;
  }
  __syncthreads();  // S1

  f32x4 acc[4][2];
  zero_acc(acc);  // GEMM1: K=288: [B0 h2r | B1 h2c | eattr-regs]
  wgemm<9>(pW1, [&](int ks, int mt) -> bf16x8 {
    if (ks < 4) return ld8(B0 + aoff + mt * 16 * STR + ks * 32);
    if (ks < 8) return ld8(B1 + aoff + mt * 16 * STR + (ks - 4) * 32);
    return ef[mt];
  }, acc, lane, wave);
  __syncthreads();  // S2
  epi_store<true>(B1, acc, b1, lane, wave);  // H -> B1
  __syncthreads();  // S3

  zero_acc(acc);  // GEMM2: ea1 = W2 x H
  wgemm<4>(pW2, [&](int ks, int mt) -> bf16x8 {
    return ld8(B1 + aoff + mt * 16 * STR + ks * 32);
  }, acc, lane, wave);
  epi_store<false>(B0, acc, b2, lane, wave);  // ea1 -> B0
  __syncthreads();  // S4
  flush_buf(B0, ea1, e0, tid);

  if (e0 < N_NODES) {
#pragma unroll
    for (int it = 0; it < 4; ++it) {
      int e = wave * 16 + it * 4 + q;
      int id = rowI[e0 + e];
      uint4 v = *(const uint4*)(h2 + (size_t)id * HID + m * 8);
      *(uint4*)(B1 + e * STR + m * 8) = v;
    }
    __syncthreads();  // S5

    zero_acc(acc);  // GEMM3: K=256: [B1 h2row | B0 ea1]
    wgemm<8>(pW3, [&](int ks, int mt) -> bf16x8 {
      if (ks < 4) return ld8(B1 + aoff + mt * 16 * STR + ks * 32);
      return ld8(B0 + aoff + mt * 16 * STR + (ks - 4) * 32);
    }, acc, lane, wave);
    __syncthreads();  // S6
    epi_store<true>(B1, acc, b3, lane, wave);  // H' -> B1
    __syncthreads();  // S7

    zero_acc(acc);  // GEMM4
    wgemm<4>(pW4, [&](int ks, int mt) -> bf16x8 {
      return ld8(B1 + aoff + mt * 16 * STR + ks * 32);
    }, acc, lane, wave);
    epi_store<false>(B0, acc, b4, lane, wave);  // h3 -> B0
    __syncthreads();  // S8
    flush_buf(B0, h3, e0, tid);
  }
  __syncthreads();  // protect B0/B1 before next tile's staging
}

__device__ __forceinline__ void gnn2_tile(
    int e0, int tid, int lane, int wave, u16* B0, u16* B1,
    const int* rowI, const int* colI, const u16* h3, u16* ea1z,
    const u16* pW5, const u16* pW67, const float* b5, const float* b67,
    float& bs0, float& bq0, float& bs1, float& bq1) {
  const int m = lane & 15, q = lane >> 4;
  const int aoff = m * STR + q * 8;
  stage_gather(rowI, colI, h3, B0, B1, e0, lane, wave);
  __syncthreads();  // S1

  f32x4 acc[4][2];
  zero_acc(acc);  // GEMM1a: ks 0..7 of K=384
  wgemm<8>(pW5, [&](int ks, int mt) -> bf16x8 {
    if (ks < 4) return ld8(B0 + aoff + mt * 16 * STR + ks * 32);
    return ld8(B1 + aoff + mt * 16 * STR + (ks - 4) * 32);
  }, acc, lane, wave);
  __syncthreads();  // S2

#pragma unroll
  for (int it = 0; it < 4; ++it) {
    int cid = tid + it * 256, e = cid >> 4, p = cid & 15;
    uint4 v = *(const uint4*)(ea1z + (size_t)(e0 + e) * HID + p * 8);
    *(uint4*)(B0 + e * STR + p * 8) = v;
  }
  __syncthreads();  // S3

  wgemm<4>(pW5 + 8 * 4096, [&](int ks, int mt) -> bf16x8 {
    return ld8(B0 + aoff + mt * 16 * STR + ks * 32);
  }, acc, lane, wave);
  epi_store<true>(B1, acc, b5, lane, wave);  // H -> B1
  __syncthreads();  // S4

  zero_acc(acc);  // GEMM2': z = W67 @ H + b67
  wgemm<4>(pW67, [&](int ks, int mt) -> bf16x8 {
    return ld8(B1 + aoff + mt * 16 * STR + ks * 32);
  }, acc, lane, wave);

  {
    const int c = lane & 15;
    const float bb0 = b67[wave * 32 + c], bb1 = b67[wave * 32 + 16 + c];
#pragma unroll
    for (int mt = 0; mt < 4; ++mt)
#pragma unroll
      for (int r = 0; r < 4; ++r) {
        float v0 = acc[mt][0][r] + bb0;
        float v1 = acc[mt][1][r] + bb1;
        bs0 += v0; bq0 += v0 * v0;
        bs1 += v1; bq1 += v1 * v1;
        int row = mt * 16 + q * 4 + r;
        B0[row * STR + wave * 32 + c] = f2bf(v0);
        B0[row * STR + wave * 32 + 16 + c] = f2bf(v1);
      }
  }
  __syncthreads();  // S5
  flush_buf(B0, ea1z, e0, tid);
  __syncthreads();  // protect before next tile's staging
}

__device__ __forceinline__ void bn_partials_store(float* partials, int rowbase,
                                                  int lane, int wave,
                                                  float bs0, float bq0,
                                                  float bs1, float bq1) {
  bs0 += __shfl_xor(bs0, 16); bs0 += __shfl_xor(bs0, 32);
  bq0 += __shfl_xor(bq0, 16); bq0 += __shfl_xor(bq0, 32);
  bs1 += __shfl_xor(bs1, 16); bs1 += __shfl_xor(bs1, 32);
  bq1 += __shfl_xor(bq1, 16); bq1 += __shfl_xor(bq1, 32);
  if (lane < 16) {
    partials[rowbase + wave * 32 + lane] = bs0;
    partials[rowbase + wave * 32 + 16 + lane] = bs1;
    partials[rowbase + 128 + wave * 32 + lane] = bq0;
    partials[rowbase + 128 + wave * 32 + 16 + lane] = bq1;
  }
}

__device__ __forceinline__ void head_group(
    int g, int tid, int lane, int wave, const u16* z,
    const float* sh_s, const float* sh_h, const float* sh_w0,
    const float* sh_w1, const float* sh_w2,
    float bb0, float bb1, float bb2, float* out) {
  const int gq = lane >> 4;
  const int p = lane & 15;
  const int c0 = p * 8;
#pragma unroll 4
  for (int it = 0; it < 16; ++it) {
    int e = g * 256 + wave * 64 + it * 4 + gq;
    if (e >= N_EDGES) break;
    uint4 v = *(const uint4*)(z + (size_t)e * HID + c0);
    unsigned wv[4] = {v.x, v.y, v.z, v.w};
    float a0 = 0.f, a1 = 0.f, a2 = 0.f;
#pragma unroll
    for (int k = 0; k < 4; ++k) {
      int ch = c0 + k * 2;
      float lo = bf2f(wv[k] & 0xffffu), hi = bf2f(wv[k] >> 16);
      float r0 = fmaxf(fmaf(lo, sh_s[ch], sh_h[ch]), 0.f);
      float r1 = fmaxf(fmaf(hi, sh_s[ch + 1], sh_h[ch + 1]), 0.f);
      a0 += r0 * sh_w0[ch] + r1 * sh_w0[ch + 1];
      a1 += r0 * sh_w1[ch] + r1 * sh_w1[ch + 1];
      a2 += r0 * sh_w2[ch] + r1 * sh_w2[ch + 1];
    }
#pragma unroll
    for (int off = 1; off < 16; off <<= 1) {
      a0 += __shfl_xor(a0, off);
      a1 += __shfl_xor(a1, off);
      a2 += __shfl_xor(a2, off);
    }
    if (p < 3) out[e * 3 + p] = (p == 0) ? a0 + bb0 : (p == 1) ? a1 + bb1 : a2 + bb2;
  }
}

struct MegaArgs {
  const float *emb, *conv_w, *conv_b, *fuse_w, *fuse_b;
  const float *fm_w1, *g2e_b2, *fm_b1, *w6;
  const float *x, *node_type;
  const int* eidx;
  const float* eattr;
  const float *b1, *b2, *b3, *b4, *b5;
  const float *bn_g, *bn_b, *w2h, *b2h;
  float* out;
  float *Mt, *C0, *Wnt, *b67, *W67f, *bnacc, *partials;
  u16 *h2, *h3, *ea1z;
  u16 *pW1, *pW2, *pW3, *pW4, *pW5, *pW67;
  const float* psrc[6];
  int pKin[6];
  int pCum[7];
};

// ---------------- prep bodies (shared) ---------------------------------------

__device__ __forceinline__ void prep1_body(
    int o, int j, float* red, float* w7s,
    const float* emb, const float* conv_w, const float* conv_b,
    const float* fuse_w, const float* fuse_b, const float* fm_w1,
    const float* g2e_b2, const float* fm_b1, const float* w6,
    float* Mt, float* C0, float* Wnt, float* b67, float* W67) {
  if (j < 128) {
    float A[21];
    float b0 = conv_b[j];
#pragma unroll
    for (int p = 0; p < 5; ++p) {
#pragma unroll
      for (int i = 0; i < 8; ++i) {
        float s = 0.f;
#pragma unroll
        for (int k = 0; k < 3; ++k) {
          int t = p + 1 - k;
          if (t >= 0 && t < 5) s += conv_w[(j * 8 + i) * 3 + k];
        }
        s *= 0.2f;
        if (i < 4) A[p * 4 + i] = s;
        else b0 += emb[p * 4 + (i - 4)] * s;
      }
    }
    A[20] = b0;
    float w = fuse_w[o * 129 + j];
    float w7 = fm_w1[o * 128 + j];
    w7s[j] = w7;
#pragma unroll
    for (int qq = 0; qq < 21; ++qq) red[qq * 129 + j] = w * A[qq];
    red[21 * 129 + j] = w7 * g2e_b2[j];
  }
  __syncthreads();
  if (j < 22) {
    float s = 0.f;
    for (int t = 0; t < 128; ++t) s += red[j * 129 + t];
    if (j < 20)       Mt[j * 128 + o] = s;
    else if (j == 20) C0[o] = s + fuse_b[o];
    else              b67[o] = s + fm_b1[o];
  }
  if (j == 0) Wnt[o] = fuse_w[o * 129 + 128];
  if (j < 128) {
    float s = 0.f;
    for (int t = 0; t < 128; ++t) s += w7s[t] * w6[t * 128 + j];
    W67[o * 128 + j] = s;
  }
}

__device__ __forceinline__ void pack_body(int bk, int tid, const float* const* psrc,
                                          const int* pKin, const int* pCum,
                                          u16* pW1, u16* pW2, u16* pW3,
                                          u16* pW4, u16* pW5, u16* pW67) {
  int mi = 0;
  while (bk >= pCum[mi + 1]) ++mi;
  int ks = bk - pCum[mi];
  const float* W = psrc[mi];
  u16* D = ((mi == 0) ? pW1 : (mi == 1) ? pW2 : (mi == 2) ? pW3
            : (mi == 3) ? pW4 : (mi == 4) ? pW5 : pW67) + ks * 4096;
  int Kin = pKin[mi];
#pragma unroll
  for (int t = 0; t < 16; ++t) {
    int el = t * 256 + tid;
    int j = el & 7, ln = (el >> 3) & 63, ntile = el >> 9;
    int k = ks * 32 + ((ln >> 4) << 3) + j;
    int n = ntile * 16 + (ln & 15);
    float v = (k < Kin) ? W[n * Kin + k] : 0.0f;
    D[el] = f2bf(v);
  }
}

__device__ __forceinline__ void encode_body(int n0, int tid, float* smemf,
                                            const float* x, const float* node_type,
                                            const float* Mt, const float* C0,
                                            const float* Wnt, u16* h2) {
  float* xs = smemf;          // [320]
  float* nts = xs + 320;      // [16]
  float* mts = nts + 16;      // [2560]
  for (int i = tid; i < 320; i += 256) xs[i] = x[n0 * 20 + i];
  if (tid < 16) nts[tid] = node_type[n0 + tid];
  for (int i = tid; i < 2560; i += 256) mts[i] = Mt[i];
  __syncthreads();
  const int nl = tid >> 4;
  const int c0 = (tid & 15) * 8;
  float nt = nts[nl];
  union { u16 s[8]; uint4 u; } o;
#pragma unroll
  for (int i = 0; i < 8; ++i) {
    int ch = c0 + i;
    float acc = C0[ch] + Wnt[ch] * nt;
#pragma unroll
    for (int qq = 0; qq < 20; ++qq) acc += xs[nl * 20 + qq] * mts[qq * 128 + ch];
    o.s[i] = f2bf(acc);
  }
  *(uint4*)(h2 + (size_t)(n0 + nl) * HID + c0) = o.u;
}

// ================= MEGA (cooperative) =======================================

__global__ __launch_bounds__(256, 4) void k_mega(MegaArgs a) {
  __shared__ __align__(16) unsigned char smem[2 * 64 * STR * 2];
  u16* B0 = (u16*)smem;
  u16* B1 = (u16*)smem + 64 * STR;
  const int tid = threadIdx.x, lane = tid & 63, wave = tid >> 6;
  const int bid = blockIdx.x;
  const int* rowI = a.eidx;
  const int* colI = a.eidx + N_EDGES;
  cg::grid_group grid = cg::this_grid();

  // P0: prep
  if (bid < 128) {
    float* red = (float*)smem;
    float* w7s = red + 22 * 129;
    prep1_body(bid, tid, red, w7s, a.emb, a.conv_w, a.conv_b, a.fuse_w, a.fuse_b,
               a.fm_w1, a.g2e_b2, a.fm_b1, a.w6, a.Mt, a.C0, a.Wnt, a.b67, a.W67f);
  } else if (bid == 128) {
    if (tid < 256) a.bnacc[tid] = 0.f;
  }
  __threadfence();
  grid.sync();

  // P1: pack + encode
  for (int t = bid; t < 41 + N_NODES / 16; t += GRID) {
    __syncthreads();
    if (t < 41) {
      pack_body(t, tid, a.psrc, a.pKin, a.pCum, a.pW1, a.pW2, a.pW3, a.pW4, a.pW5, a.pW67);
    } else {
      encode_body((t - 41) * 16, tid, (float*)smem, a.x, a.node_type, a.Mt, a.C0,
                  a.Wnt, a.h2);
    }
  }
  __threadfence();
  grid.sync();

  // P2: gnn1
  for (int t = bid; t < NBLK; t += GRID)
    gnn1_tile(t * 64, tid, lane, wave, B0, B1, rowI, colI, a.eattr, a.h2,
              a.pW1, a.pW2, a.pW3, a.pW4, a.b1, a.b2, a.b3, a.b4, a.ea1z, a.h3);
  __threadfence();
  grid.sync();

  // P3: gnn2 + BN partials (one private row per block)
  {
    float bs0 = 0.f, bq0 = 0.f, bs1 = 0.f, bq1 = 0.f;
    for (int t = bid; t < NBLK; t += GRID)
      gnn2_tile(t * 64, tid, lane, wave, B0, B1, rowI, colI, a.h3, a.ea1z,
                a.pW5, a.pW67, a.b5, a.b67, bs0, bq0, bs1, bq1);
    bn_partials_store(a.partials, bid * 256, lane, wave, bs0, bq0, bs1, bq1);
  }
  __threadfence();
  grid.sync();

  // P4: reduce partials (GRID rows) -> bnacc
  if (bid < 64) {
    float s = 0.f;
    for (int r = bid; r < GRID; r += 64) s += a.partials[r * 256 + tid];
    atomicAdd(&a.bnacc[tid], s);
  }
  __threadfence();
  grid.sync();

  // P5: head
  {
    float* sh_s = (float*)smem;
    float* sh_h = sh_s + 128;
    float* sh_w0 = sh_h + 128;
    float* sh_w1 = sh_w0 + 128;
    float* sh_w2 = sh_w1 + 128;
    if (tid < 128) {
      const float inv = 1.0f / (float)N_EDGES;
      float mu = a.bnacc[tid] * inv;
      float var = a.bnacc[128 + tid] * inv - mu * mu;
      float sc = a.bn_g[tid] * rsqrtf(var + 1e-5f);
      sh_s[tid] = sc;
      sh_h[tid] = a.bn_b[tid] - mu * sc;
      sh_w0[tid] = a.w2h[tid];
      sh_w1[tid] = a.w2h[128 + tid];
      sh_w2[tid] = a.w2h[256 + tid];
    }
    __syncthreads();
    const float bb0 = a.b2h[0], bb1 = a.b2h[1], bb2 = a.b2h[2];
    for (int g = bid; g < (N_EDGES + 255) / 256; g += GRID)
      head_group(g, tid, lane, wave, a.ea1z, sh_s, sh_h, sh_w0, sh_w1, sh_w2,
                 bb0, bb1, bb2, a.out);
  }
}

// ================= fallback kernels (r12-proven path) ========================

__global__ __launch_bounds__(128) void k_prep1(MegaArgs a) {
  __shared__ float red[22 * 129];
  __shared__ float w7s[128];
  prep1_body(blockIdx.x, threadIdx.x, red, w7s, a.emb, a.conv_w, a.conv_b,
             a.fuse_w, a.fuse_b, a.fm_w1, a.g2e_b2, a.fm_b1, a.w6,
             a.Mt, a.C0, a.Wnt, a.b67, a.W67f);
}

__global__ __launch_bounds__(256) void k_prep2(MegaArgs a) {
  __shared__ __align__(16) float smemf[320 + 16 + 2560];
  if (blockIdx.x < 41) {
    pack_body(blockIdx.x, threadIdx.x, a.psrc, a.pKin, a.pCum,
              a.pW1, a.pW2, a.pW3, a.pW4, a.pW5, a.pW67);
    return;
  }
  encode_body(((int)blockIdx.x - 41) * 16, threadIdx.x, smemf, a.x, a.node_type,
              a.Mt, a.C0, a.Wnt, a.h2);
}

__global__ __launch_bounds__(256, 4) void k_gnn1(MegaArgs a) {
  __shared__ __align__(16) u16 B0[64 * STR], B1[64 * STR];
  const int tid = threadIdx.x;
  gnn1_tile((int)blockIdx.x * 64, tid, tid & 63, tid >> 6, B0, B1,
            a.eidx, a.eidx + N_EDGES, a.eattr, a.h2,
            a.pW1, a.pW2, a.pW3, a.pW4, a.b1, a.b2, a.b3, a.b4, a.ea1z, a.h3);
}

__global__ __launch_bounds__(256, 4) void k_gnn2(MegaArgs a) {
  __shared__ __align__(16) u16 B0[64 * STR], B1[64 * STR];
  const int tid = threadIdx.x, lane = tid & 63, wave = tid >> 6;
  float bs0 = 0.f, bq0 = 0.f, bs1 = 0.f, bq1 = 0.f;
  gnn2_tile((int)blockIdx.x * 64, tid, lane, wave, B0, B1,
            a.eidx, a.eidx + N_EDGES, a.h3, a.ea1z, a.pW5, a.pW67, a.b5, a.b67,
            bs0, bq0, bs1, bq1);
  bn_partials_store(a.partials, (int)blockIdx.x * 256, lane, wave, bs0, bq0, bs1, bq1);
}

__global__ void k_reduce(const float* __restrict__ partials, float* __restrict__ bnacc,
                         int nrows) {
  int t = threadIdx.x;  // 256
  float s = 0.f;
  for (int b = blockIdx.x; b < nrows; b += 64) s += partials[b * 256 + t];
  atomicAdd(&bnacc[t], s);
}

__global__ __launch_bounds__(256) void k_head(MegaArgs a) {
  __shared__ float sh_s[128], sh_h[128], sh_w0[128], sh_w1[128], sh_w2[128];
  const int tid = threadIdx.x;
  if (tid < 128) {
    const float inv = 1.0f / (float)N_EDGES;
    float mu = a.bnacc[tid] * inv;
    float var = a.bnacc[128 + tid] * inv - mu * mu;
    float sc = a.bn_g[tid] * rsqrtf(var + 1e-5f);
    sh_s[tid] = sc;
    sh_h[tid] = a.bn_b[tid] - mu * sc;
    sh_w0[tid] = a.w2h[tid];
    sh_w1[tid] = a.w2h[128 + tid];
    sh_w2[tid] = a.w2h[256 + tid];
  }
  __syncthreads();
  head_group(blockIdx.x, tid, tid & 63, tid >> 6, a.ea1z, sh_s, sh_h,
             sh_w0, sh_w1, sh_w2, a.b2h[0], a.b2h[1], a.b2h[2], a.out);
}

extern "C" void kernel_launch(void* const* d_in, const int* in_sizes, int n_in,
                              void* d_out, int out_size, void* d_ws, size_t ws_size,
                              hipStream_t stream) {
  MegaArgs a;
  a.x         = (const float*)d_in[0];
  a.eidx      = (const int*)d_in[1];
  a.eattr     = (const float*)d_in[2];
  a.node_type = (const float*)d_in[4];
  a.emb       = (const float*)d_in[5];
  a.conv_w    = (const float*)d_in[6];
  a.conv_b    = (const float*)d_in[7];
  a.fuse_w    = (const float*)d_in[8];
  a.fuse_b    = (const float*)d_in[9];
  const float* g1e_w1 = (const float*)d_in[10];
  a.b1        = (const float*)d_in[11];
  const float* g1e_w2 = (const float*)d_in[12];
  a.b2        = (const float*)d_in[13];
  const float* g1n_w1 = (const float*)d_in[14];
  a.b3        = (const float*)d_in[15];
  const float* g1n_w2 = (const float*)d_in[16];
  a.b4        = (const float*)d_in[17];
  const float* g2e_w1 = (const float*)d_in[18];
  a.b5        = (const float*)d_in[19];
  a.w6        = (const float*)d_in[20];  // g2e_w2
  a.g2e_b2    = (const float*)d_in[21];
  // d_in[22..25] = g2n_* : dead code in the reference (output unused)
  a.fm_w1     = (const float*)d_in[26];
  a.fm_b1     = (const float*)d_in[27];
  a.bn_g      = (const float*)d_in[28];
  a.bn_b      = (const float*)d_in[29];
  a.w2h       = (const float*)d_in[30];
  a.b2h       = (const float*)d_in[31];
  a.out       = (float*)d_out;

  char* ws = (char*)d_ws;
  size_t off = 0;
  auto take = [&](size_t bytes) {
    void* p = ws + off;
    off = (off + bytes + 255) & ~(size_t)255;
    return p;
  };
  a.h2   = (u16*)take((size_t)N_NODES * HID * 2);
  a.h3   = (u16*)take((size_t)20032 * HID * 2);
  a.ea1z = (u16*)take((size_t)N_EDGES * HID * 2);
  a.Mt    = (float*)take(20 * 128 * 4);
  a.C0    = (float*)take(128 * 4);
  a.Wnt   = (float*)take(128 * 4);
  a.bnacc = (float*)take(256 * 4);
  a.b67   = (float*)take(128 * 4);
  a.W67f  = (float*)take(128 * 128 * 4);
  a.partials = (float*)take((size_t)NBLK * 256 * 4);  // covers GRID and NBLK rows
  a.pW1  = (u16*)take(9 * 4096 * 2);
  a.pW2  = (u16*)take(4 * 4096 * 2);
  a.pW3  = (u16*)take(8 * 4096 * 2);
  a.pW4  = (u16*)take(4 * 4096 * 2);
  a.pW5  = (u16*)take(12 * 4096 * 2);
  a.pW67 = (u16*)take(4 * 4096 * 2);

  const float* srcs[6] = {g1e_w1, g1e_w2, g1n_w1, g1n_w2, g2e_w1, a.W67f};
  int kins[6] = {260, 128, 256, 128, 384, 128};
  int kst[6] = {9, 4, 8, 4, 12, 4};
  int cum = 0;
  for (int i = 0; i < 6; ++i) {
    a.psrc[i] = srcs[i];
    a.pKin[i] = kins[i];
    a.pCum[i] = cum;
    cum += kst[i];
  }
  a.pCum[6] = cum;  // 41

  void* params[] = {(void*)&a};
  hipError_t err = hipLaunchCooperativeKernel((const void*)k_mega, dim3(GRID),
                                              dim3(256), params, 0, stream);
  if (err != hipSuccess) {
    // deterministic fallback: r12-proven multi-kernel path
    hipMemsetAsync(a.bnacc, 0, 256 * 4, stream);
    k_prep1<<<128, 128, 0, stream>>>(a);
    k_prep2<<<41 + N_NODES / 16, 256, 0, stream>>>(a);
    k_gnn1<<<NBLK, 256, 0, stream>>>(a);
    k_gnn2<<<NBLK, 256, 0, stream>>>(a);
    k_reduce<<<64, 256, 0, stream>>>(a.partials, a.bnacc, NBLK);
    k_head<<<(N_EDGES + 255) / 256, 256, 0, stream>>>(a);
  }
}

// Round 16
// 410.300 us; speedup vs baseline: 2.7005x; 2.7005x over previous
//
#include <hip/hip_runtime.h>

#define N_NODES 20000
#define N_EDGES 200000
#define HID 128
#define STR 136   // LDS row stride in u16: 272B rows -> every b128 access 16B-aligned
#define NBLK 3125 // 64-edge tiles

typedef unsigned short u16;
using bf16x8 = __attribute__((ext_vector_type(8))) __bf16;
using f32x4  = __attribute__((ext_vector_type(4))) float;

__device__ __forceinline__ u16 f2bf(float f) {
  union { float f; unsigned u; } v; v.f = f;
  unsigned u = v.u;
  return (u16)((u + 0x7FFFu + ((u >> 16) & 1u)) >> 16);
}
__device__ __forceinline__ float bf2f(unsigned s) {
  union { unsigned u; float f; } v; v.u = s << 16;
  return v.f;
}
__device__ __forceinline__ bf16x8 ld8(const u16* p) { return *(const bf16x8*)p; }

__device__ __forceinline__ void zero_acc(f32x4 acc[4][2]) {
#pragma unroll
  for (int i = 0; i < 4; ++i) {
    acc[i][0] = (f32x4){0.f, 0.f, 0.f, 0.f};
    acc[i][1] = (f32x4){0.f, 0.f, 0.f, 0.f};
  }
}

// r12-proven GEMM: wave owns 4 m-tiles x 2 n-tiles, depth-2 B ring.
template <int KSTEPS, typename AF>
__device__ __forceinline__ void wgemm(const u16* __restrict__ PW, AF afrag,
                                      f32x4 acc[4][2], int lane, int wave) {
  const u16* pb = PW + (wave * 2 * 64 + lane) * 8;
  bf16x8 b0[2], b1[2];
  b0[0] = ld8(pb);
  b1[0] = ld8(pb + 512);
#pragma unroll
  for (int ks = 0; ks < KSTEPS; ++ks) {
    const int cur = ks & 1, nxt = cur ^ 1;
    if (ks + 1 < KSTEPS) {
      b0[nxt] = ld8(pb + (ks + 1) * 4096);
      b1[nxt] = ld8(pb + (ks + 1) * 4096 + 512);
    }
#pragma unroll
    for (int mt = 0; mt < 4; ++mt) {
      bf16x8 a = afrag(ks, mt);
      acc[mt][0] = __builtin_amdgcn_mfma_f32_16x16x32_bf16(a, b0[cur], acc[mt][0], 0, 0, 0);
      acc[mt][1] = __builtin_amdgcn_mfma_f32_16x16x32_bf16(a, b1[cur], acc[mt][1], 0, 0, 0);
    }
  }
}

// C/D: row(edge) = mt*16 + (lane>>4)*4 + r, col(ch) = wave*32 + nt*16 + (lane&15).
template <bool RELU>
__device__ __forceinline__ void epi_store(u16* buf, const f32x4 acc[4][2],
                                          const float* __restrict__ bias,
                                          int lane, int wave) {
  const int c = lane & 15, q = lane >> 4;
  const float bb0 = bias[wave * 32 + c], bb1 = bias[wave * 32 + 16 + c];
#pragma unroll
  for (int mt = 0; mt < 4; ++mt)
#pragma unroll
    for (int nt = 0; nt < 2; ++nt) {
      const float bb = nt ? bb1 : bb0;
      const int col = wave * 32 + nt * 16 + c;
#pragma unroll
      for (int r = 0; r < 4; ++r) {
        float v = acc[mt][nt][r] + bb;
        if (RELU) v = fmaxf(v, 0.f);
        buf[(mt * 16 + q * 4 + r) * STR + col] = f2bf(v);
      }
    }
}

__device__ __forceinline__ void flush_buf(const u16* buf, u16* __restrict__ gout,
                                          int e0, int tid) {
#pragma unroll
  for (int it = 0; it < 4; ++it) {
    int cid = tid + it * 256, e = cid >> 4, p = cid & 15;
    uint4 v = *(const uint4*)(buf + e * STR + p * 8);
    *(uint4*)(gout + (size_t)(e0 + e) * HID + p * 8) = v;
  }
}

// TA-friendly gather: 16 lanes cooperate per row -> 8 distinct lines/instr.
__device__ __forceinline__ void stage_gather(const int* __restrict__ rowI,
                                             const int* __restrict__ colI,
                                             const u16* __restrict__ htab,
                                             u16* B0, u16* B1,
                                             int e0, int lane, int wave) {
  const int r = lane >> 4, p = lane & 15;
#pragma unroll
  for (int it = 0; it < 8; ++it) {
    int j = wave * 32 + it * 4 + r;  // 0..127
    int e = j & 63;
    int id = (j < 64) ? rowI[e0 + e] : colI[e0 + e];
    uint4 v = *(const uint4*)(htab + (size_t)id * HID + p * 8);
    *(uint4*)(((j < 64) ? B0 : B1) + e * STR + p * 8) = v;
  }
}

// ---- unified prep: blocks 0..40 pack weights (mi=5 computes W67 slice + b67 +
// zero bnacc in-block); blocks 41..197 encode 128 nodes each, computing the
// encoder fold (Mt/C0/Wnt) in-block via coalesced fuse_w rows + shuffle trees ----
struct PrepArgs {
  const float* src[5];     // packed-from-global matrices (mi 0..4)
  u16* dst[6];
  int Kin[6];
  int ksCum[7];
  const float *w6, *w7;    // g2e_w2, fm_w1 (for W67 slices)
  const float *g2e_b2, *fm_b1;
  const float *emb, *conv_w, *conv_b, *fuse_w, *fuse_b;
  const float *x, *node_type;
  float *b67, *bnacc;
  u16* h2;
};

__global__ __launch_bounds__(256) void k_prep(PrepArgs pa) {
  __shared__ float smemf[8192];  // 32KB, branch-aliased
  const int tid = threadIdx.x;
  const int bid = blockIdx.x;

  if (bid < 41) {  // ---------------- pack branch ----------------
    int bk = bid, mi = 0;
    while (bk >= pa.ksCum[mi + 1]) ++mi;
    int ks = bk - pa.ksCum[mi];
    u16* D = pa.dst[mi] + ks * 4096;
    if (mi == 5) {
      // W67 slice: Wsl[n][kk] = sum_j w7[n][j]*w6[j][k0+kk], k0 = ks*32
      float* w6s = smemf;          // [128][32]
      float* Wsl = smemf + 4096;   // [128][32]
      const int k0 = ks * 32;
      const int kk = tid & 31, jg = tid >> 5;  // 8 j/n-groups
#pragma unroll
      for (int rep = 0; rep < 16; ++rep) {
        int j = jg + rep * 8;
        w6s[j * 32 + kk] = pa.w6[j * 128 + k0 + kk];
      }
      __syncthreads();
#pragma unroll
      for (int ni = 0; ni < 16; ++ni) {
        int n = jg * 16 + ni;
        float s = 0.f;
        for (int j = 0; j < 128; ++j) s += pa.w7[n * 128 + j] * w6s[j * 32 + kk];
        Wsl[n * 32 + kk] = s;
      }
      __syncthreads();
#pragma unroll
      for (int t = 0; t < 16; ++t) {
        int el = t * 256 + tid;
        int j = el & 7, ln = (el >> 3) & 63, ntile = el >> 9;
        int kkl = ((ln >> 4) << 3) + j;       // 0..31
        int n = ntile * 16 + (ln & 15);
        D[el] = f2bf(Wsl[n * 32 + kkl]);
      }
      if (ks == 0) {  // block 37: b67 + zero bnacc (replaces hipMemsetAsync)
        if (tid < 128) {
          float s = 0.f;
          for (int j = 0; j < 128; ++j) s += pa.w7[tid * 128 + j] * pa.g2e_b2[j];
          pa.b67[tid] = s + pa.fm_b1[tid];
        }
        pa.bnacc[tid] = 0.f;
      }
    } else {
      const float* W = pa.src[mi];
      int Kin = pa.Kin[mi];
#pragma unroll
      for (int t = 0; t < 16; ++t) {
        int el = t * 256 + tid;
        int j = el & 7, ln = (el >> 3) & 63, ntile = el >> 9;
        int k = ks * 32 + ((ln >> 4) << 3) + j;
        int n = ntile * 16 + (ln & 15);
        float v = (k < Kin) ? W[n * Kin + k] : 0.0f;
        D[el] = f2bf(v);
      }
    }
    return;
  }

  // ---------------- encode branch: 128 nodes per block ----------------
  const int lane = tid & 63, wave = tid >> 6;
  const int n0 = (bid - 41) * 128;
  const int ncount = (N_NODES - n0 < 128) ? (N_NODES - n0) : 128;
  float* As  = smemf;          // [128][21]
  float* mts = As + 2688;      // [20][128]
  float* C0s = mts + 2560;     // [128]
  float* Wns = C0s + 128;      // [128]
  float* xs  = Wns + 128;      // [128][20]
  float* nts = xs + 2560;      // [128]

  if (tid < 128) {  // conv fold -> A rows
    const int j = tid;
    float A[21];
    float b0 = pa.conv_b[j];
#pragma unroll
    for (int p = 0; p < 5; ++p) {
#pragma unroll
      for (int i = 0; i < 8; ++i) {
        float s = 0.f;
#pragma unroll
        for (int k = 0; k < 3; ++k) {
          int t = p + 1 - k;
          if (t >= 0 && t < 5) s += pa.conv_w[(j * 8 + i) * 3 + k];
        }
        s *= 0.2f;
        if (i < 4) A[p * 4 + i] = s;
        else b0 += pa.emb[p * 4 + (i - 4)] * s;
      }
    }
    A[20] = b0;
#pragma unroll
    for (int qq = 0; qq < 21; ++qq) As[j * 21 + qq] = A[qq];
    if (j < ncount) nts[j] = pa.node_type[n0 + j];
  } else {  // concurrent x staging
    for (int i = tid - 128; i < ncount * 20; i += 128) xs[i] = pa.x[n0 * 20 + i];
  }
  __syncthreads();

  // fuse fold: wave handles o = wave*32 .. +31; lanes = j (coalesced fuse_w rows)
  for (int oi = 0; oi < 32; ++oi) {
    const int o = wave * 32 + oi;
    float fw0 = pa.fuse_w[o * 129 + lane];
    float fw1 = pa.fuse_w[o * 129 + 64 + lane];
#pragma unroll
    for (int qq = 0; qq < 21; ++qq) {
      float t = fw0 * As[lane * 21 + qq] + fw1 * As[(lane + 64) * 21 + qq];
      t += __shfl_xor(t, 1);  t += __shfl_xor(t, 2);  t += __shfl_xor(t, 4);
      t += __shfl_xor(t, 8);  t += __shfl_xor(t, 16); t += __shfl_xor(t, 32);
      if (lane == 0) {
        if (qq < 20) mts[qq * 128 + o] = t;
        else C0s[o] = t + pa.fuse_b[o];
      }
    }
    if (lane == 0) Wns[o] = pa.fuse_w[o * 129 + 128];
  }
  __syncthreads();

  // encode: 16 nodes per pass
  for (int base = 0; base < 128; base += 16) {
    const int nl = base + (tid >> 4);
    if (nl < ncount) {
      const int c0 = (tid & 15) * 8;
      float nt = nts[nl];
      union { u16 s[8]; uint4 u; } o;
#pragma unroll
      for (int i = 0; i < 8; ++i) {
        int ch = c0 + i;
        float acc = C0s[ch] + Wns[ch] * nt;
#pragma unroll
        for (int qq = 0; qq < 20; ++qq) acc += xs[nl * 20 + qq] * mts[qq * 128 + ch];
        o.s[i] = f2bf(acc);
      }
      *(uint4*)(pa.h2 + (size_t)(n0 + nl) * HID + c0) = o.u;
    }
  }
}

// ---- gnn1: unchanged (r12-proven) ----
__global__ __launch_bounds__(256, 4) void k_gnn1(
    const int* __restrict__ eidx, const float* __restrict__ eattr,
    const u16* __restrict__ h2, const u16* __restrict__ pW1, const u16* __restrict__ pW2,
    const u16* __restrict__ pW3, const u16* __restrict__ pW4, const float* __restrict__ b1,
    const float* __restrict__ b2, const float* __restrict__ b3, const float* __restrict__ b4,
    u16* __restrict__ ea1, u16* __restrict__ h3) {
  __shared__ __align__(16) u16 B0[64 * STR], B1[64 * STR];
  const int tid = threadIdx.x, lane = tid & 63, wave = tid >> 6;
  const int e0 = blockIdx.x * 64;
  const int m = lane & 15, q = lane >> 4;
  const int aoff = m * STR + q * 8;
  const int* rowI = eidx;
  const int* colI = eidx + N_EDGES;

  stage_gather(rowI, colI, h2, B0, B1, e0, lane, wave);

  bf16x8 ef[4];
#pragma unroll
  for (int mt = 0; mt < 4; ++mt) {
    union { u16 s[8]; uint4 u; bf16x8 v; } t;
    t.u = make_uint4(0u, 0u, 0u, 0u);
    if (q == 0) {
      float4 a = *(const float4*)(eattr + (size_t)(e0 + mt * 16 + m) * 4);
      t.s[0] = f2bf(a.x); t.s[1] = f2bf(a.y); t.s[2] = f2bf(a.z); t.s[3] = f2bf(a.w);
    }
    ef[mt] = t.v;
  }
  __syncthreads();  // S1

  f32x4 acc[4][2];
  zero_acc(acc);  // GEMM1: K=288: [B0 h2r | B1 h2c | eattr-regs]
  wgemm<9>(pW1, [&](int ks, int mt) -> bf16x8 {
    if (ks < 4) return ld8(B0 + aoff + mt * 16 * STR + ks * 32);
    if (ks < 8) return ld8(B1 + aoff + mt * 16 * STR + (ks - 4) * 32);
    return ef[mt];
  }, acc, lane, wave);
  __syncthreads();  // S2
  epi_store<true>(B1, acc, b1, lane, wave);  // H -> B1
  __syncthreads();  // S3

  zero_acc(acc);  // GEMM2: ea1 = W2 x H
  wgemm<4>(pW2, [&](int ks, int mt) -> bf16x8 {
    return ld8(B1 + aoff + mt * 16 * STR + ks * 32);
  }, acc, lane, wave);
  epi_store<false>(B0, acc, b2, lane, wave);  // ea1 -> B0
  __syncthreads();  // S4
  flush_buf(B0, ea1, e0, tid);

  if (e0 < N_NODES) {
#pragma unroll
    for (int it = 0; it < 4; ++it) {
      int e = wave * 16 + it * 4 + q;
      int id = rowI[e0 + e];
      uint4 v = *(const uint4*)(h2 + (size_t)id * HID + m * 8);
      *(uint4*)(B1 + e * STR + m * 8) = v;
    }
    __syncthreads();  // S5

    zero_acc(acc);  // GEMM3: K=256: [B1 h2row | B0 ea1]
    wgemm<8>(pW3, [&](int ks, int mt) -> bf16x8 {
      if (ks < 4) return ld8(B1 + aoff + mt * 16 * STR + ks * 32);
      return ld8(B0 + aoff + mt * 16 * STR + (ks - 4) * 32);
    }, acc, lane, wave);
    __syncthreads();  // S6
    epi_store<true>(B1, acc, b3, lane, wave);  // H' -> B1
    __syncthreads();  // S7

    zero_acc(acc);  // GEMM4
    wgemm<4>(pW4, [&](int ks, int mt) -> bf16x8 {
      return ld8(B1 + aoff + mt * 16 * STR + ks * 32);
    }, acc, lane, wave);
    epi_store<false>(B0, acc, b4, lane, wave);  // h3 -> B0
    __syncthreads();  // S8
    flush_buf(B0, h3, e0, tid);
  }
}

// ---- gnn2: unchanged (r12-proven); BN partials to private per-block rows ----
__global__ __launch_bounds__(256, 4) void k_gnn2(
    const int* __restrict__ eidx, const u16* __restrict__ h3, u16* ea1z,
    const u16* __restrict__ pW5, const u16* __restrict__ pW67,
    const float* __restrict__ b5, const float* __restrict__ b67,
    float* __restrict__ partials) {
  __shared__ __align__(16) u16 B0[64 * STR], B1[64 * STR];
  const int tid = threadIdx.x, lane = tid & 63, wave = tid >> 6;
  const int e0 = blockIdx.x * 64;
  const int m = lane & 15, q = lane >> 4;
  const int aoff = m * STR + q * 8;
  const int* rowI = eidx;
  const int* colI = eidx + N_EDGES;

  stage_gather(rowI, colI, h3, B0, B1, e0, lane, wave);
  __syncthreads();  // S1

  f32x4 acc[4][2];
  zero_acc(acc);  // GEMM1a: ks 0..7 of K=384
  wgemm<8>(pW5, [&](int ks, int mt) -> bf16x8 {
    if (ks < 4) return ld8(B0 + aoff + mt * 16 * STR + ks * 32);
    return ld8(B1 + aoff + mt * 16 * STR + (ks - 4) * 32);
  }, acc, lane, wave);
  __syncthreads();  // S2

#pragma unroll
  for (int it = 0; it < 4; ++it) {
    int cid = tid + it * 256, e = cid >> 4, p = cid & 15;
    uint4 v = *(const uint4*)(ea1z + (size_t)(e0 + e) * HID + p * 8);
    *(uint4*)(B0 + e * STR + p * 8) = v;
  }
  __syncthreads();  // S3

  wgemm<4>(pW5 + 8 * 4096, [&](int ks, int mt) -> bf16x8 {
    return ld8(B0 + aoff + mt * 16 * STR + ks * 32);
  }, acc, lane, wave);
  epi_store<true>(B1, acc, b5, lane, wave);  // H -> B1
  __syncthreads();  // S4

  zero_acc(acc);  // GEMM2': z = W67 @ H + b67
  wgemm<4>(pW67, [&](int ks, int mt) -> bf16x8 {
    return ld8(B1 + aoff + mt * 16 * STR + ks * 32);
  }, acc, lane, wave);

  {
    const int c = lane & 15;
    const float bb0 = b67[wave * 32 + c], bb1 = b67[wave * 32 + 16 + c];
    float s0 = 0.f, q0 = 0.f, s1 = 0.f, q1 = 0.f;
#pragma unroll
    for (int mt = 0; mt < 4; ++mt)
#pragma unroll
      for (int r = 0; r < 4; ++r) {
        float v0 = acc[mt][0][r] + bb0;
        float v1 = acc[mt][1][r] + bb1;
        s0 += v0; q0 += v0 * v0;
        s1 += v1; q1 += v1 * v1;
        int row = mt * 16 + q * 4 + r;
        B0[row * STR + wave * 32 + c] = f2bf(v0);
        B0[row * STR + wave * 32 + 16 + c] = f2bf(v1);
      }
    s0 += __shfl_xor(s0, 16); s0 += __shfl_xor(s0, 32);
    q0 += __shfl_xor(q0, 16); q0 += __shfl_xor(q0, 32);
    s1 += __shfl_xor(s1, 16); s1 += __shfl_xor(s1, 32);
    q1 += __shfl_xor(q1, 16); q1 += __shfl_xor(q1, 32);
    if (lane < 16) {
      int base = (int)blockIdx.x * 256;
      partials[base + wave * 32 + lane] = s0;
      partials[base + wave * 32 + 16 + lane] = s1;
      partials[base + 128 + wave * 32 + lane] = q0;
      partials[base + 128 + wave * 32 + 16 + lane] = q1;
    }
  }
  __syncthreads();  // S5
  flush_buf(B0, ea1z, e0, tid);
}

__global__ void k_reduce(const float* __restrict__ partials, float* __restrict__ bnacc,
                         int nrows) {
  int t = threadIdx.x;  // 256
  float s = 0.f;
  for (int b = blockIdx.x; b < nrows; b += 64) s += partials[b * 256 + t];
  atomicAdd(&bnacc[t], s);
}

// ---- head: unchanged (r12-proven) ----
__global__ __launch_bounds__(256) void k_head(const u16* __restrict__ z,
                                              const float* __restrict__ bnacc,
                                              const float* __restrict__ bn_g,
                                              const float* __restrict__ bn_b,
                                              const float* __restrict__ w2,
                                              const float* __restrict__ b2,
                                              float* __restrict__ out) {
  __shared__ float sh_s[128], sh_h[128], sh_w0[128], sh_w1[128], sh_w2[128];
  const int tid = threadIdx.x;
  if (tid < 128) {
    const float inv = 1.0f / (float)N_EDGES;
    float mu = bnacc[tid] * inv;
    float var = bnacc[128 + tid] * inv - mu * mu;
    float sc = bn_g[tid] * rsqrtf(var + 1e-5f);
    sh_s[tid] = sc;
    sh_h[tid] = bn_b[tid] - mu * sc;
    sh_w0[tid] = w2[tid];
    sh_w1[tid] = w2[128 + tid];
    sh_w2[tid] = w2[256 + tid];
  }
  __syncthreads();
  const int lane = tid & 63, wave = tid >> 6;
  const int g = lane >> 4;       // edge-in-quad
  const int p = lane & 15;       // piece
  const int c0 = p * 8;
  const float bb0 = b2[0], bb1 = b2[1], bb2 = b2[2];
#pragma unroll 4
  for (int it = 0; it < 16; ++it) {
    int e = (int)blockIdx.x * 256 + wave * 64 + it * 4 + g;
    if (e >= N_EDGES) break;
    uint4 v = *(const uint4*)(z + (size_t)e * HID + c0);
    unsigned wv[4] = {v.x, v.y, v.z, v.w};
    float a0 = 0.f, a1 = 0.f, a2 = 0.f;
#pragma unroll
    for (int k = 0; k < 4; ++k) {
      int ch = c0 + k * 2;
      float lo = bf2f(wv[k] & 0xffffu), hi = bf2f(wv[k] >> 16);
      float r0 = fmaxf(fmaf(lo, sh_s[ch], sh_h[ch]), 0.f);
      float r1 = fmaxf(fmaf(hi, sh_s[ch + 1], sh_h[ch + 1]), 0.f);
      a0 += r0 * sh_w0[ch] + r1 * sh_w0[ch + 1];
      a1 += r0 * sh_w1[ch] + r1 * sh_w1[ch + 1];
      a2 += r0 * sh_w2[ch] + r1 * sh_w2[ch + 1];
    }
#pragma unroll
    for (int off = 1; off < 16; off <<= 1) {
      a0 += __shfl_xor(a0, off);
      a1 += __shfl_xor(a1, off);
      a2 += __shfl_xor(a2, off);
    }
    if (p < 3) out[e * 3 + p] = (p == 0) ? a0 + bb0 : (p == 1) ? a1 + bb1 : a2 + bb2;
  }
}

extern "C" void kernel_launch(void* const* d_in, const int* in_sizes, int n_in,
                              void* d_out, int out_size, void* d_ws, size_t ws_size,
                              hipStream_t stream) {
  const float* x         = (const float*)d_in[0];
  const int* eidx        = (const int*)d_in[1];
  const float* eattr     = (const float*)d_in[2];
  const float* node_type = (const float*)d_in[4];
  const float* emb       = (const float*)d_in[5];
  const float* conv_w    = (const float*)d_in[6];
  const float* conv_b    = (const float*)d_in[7];
  const float* fuse_w    = (const float*)d_in[8];
  const float* fuse_b    = (const float*)d_in[9];
  const float* g1e_w1    = (const float*)d_in[10];
  const float* g1e_b1    = (const float*)d_in[11];
  const float* g1e_w2    = (const float*)d_in[12];
  const float* g1e_b2    = (const float*)d_in[13];
  const float* g1n_w1    = (const float*)d_in[14];
  const float* g1n_b1    = (const float*)d_in[15];
  const float* g1n_w2    = (const float*)d_in[16];
  const float* g1n_b2    = (const float*)d_in[17];
  const float* g2e_w1    = (const float*)d_in[18];
  const float* g2e_b1    = (const float*)d_in[19];
  const float* g2e_w2    = (const float*)d_in[20];
  const float* g2e_b2    = (const float*)d_in[21];
  // d_in[22..25] = g2n_* : dead code in the reference (output unused)
  const float* fm_w1     = (const float*)d_in[26];
  const float* fm_b1     = (const float*)d_in[27];
  const float* bn_g      = (const float*)d_in[28];
  const float* bn_b      = (const float*)d_in[29];
  const float* fm_w2     = (const float*)d_in[30];
  const float* fm_b2     = (const float*)d_in[31];
  float* out = (float*)d_out;

  char* ws = (char*)d_ws;
  size_t off = 0;
  auto take = [&](size_t bytes) {
    void* p = ws + off;
    off = (off + bytes + 255) & ~(size_t)255;
    return p;
  };
  u16* h2   = (u16*)take((size_t)N_NODES * HID * 2);
  u16* h3   = (u16*)take((size_t)20032 * HID * 2);
  u16* ea1z = (u16*)take((size_t)N_EDGES * HID * 2);
  float* bnacc = (float*)take(256 * 4);
  float* b67   = (float*)take(128 * 4);
  float* partials = (float*)take((size_t)NBLK * 256 * 4);
  u16* pW1  = (u16*)take(9 * 4096 * 2);
  u16* pW2  = (u16*)take(4 * 4096 * 2);
  u16* pW3  = (u16*)take(8 * 4096 * 2);
  u16* pW4  = (u16*)take(4 * 4096 * 2);
  u16* pW5  = (u16*)take(12 * 4096 * 2);
  u16* pW67 = (u16*)take(4 * 4096 * 2);

  PrepArgs pa;
  const float* srcs[5] = {g1e_w1, g1e_w2, g1n_w1, g1n_w2, g2e_w1};
  u16* dsts[6] = {pW1, pW2, pW3, pW4, pW5, pW67};
  int kins[6] = {260, 128, 256, 128, 384, 128};
  int kst[6] = {9, 4, 8, 4, 12, 4};
  int cum = 0;
  for (int i = 0; i < 6; ++i) {
    if (i < 5) pa.src[i] = srcs[i];
    pa.dst[i] = dsts[i];
    pa.Kin[i] = kins[i];
    pa.ksCum[i] = cum;
    cum += kst[i];
  }
  pa.ksCum[6] = cum;  // 41
  pa.w6 = g2e_w2; pa.w7 = fm_w1;
  pa.g2e_b2 = g2e_b2; pa.fm_b1 = fm_b1;
  pa.emb = emb; pa.conv_w = conv_w; pa.conv_b = conv_b;
  pa.fuse_w = fuse_w; pa.fuse_b = fuse_b;
  pa.x = x; pa.node_type = node_type;
  pa.b67 = b67; pa.bnacc = bnacc; pa.h2 = h2;

  const int NENC = (N_NODES + 127) / 128;  // 157
  k_prep<<<41 + NENC, 256, 0, stream>>>(pa);
  k_gnn1<<<NBLK, 256, 0, stream>>>(eidx, eattr, h2, pW1, pW2, pW3, pW4,
                                   g1e_b1, g1e_b2, g1n_b1, g1n_b2, ea1z, h3);
  k_gnn2<<<NBLK, 256, 0, stream>>>(eidx, h3, ea1z, pW5, pW67,
                                   g2e_b1, b67, partials);
  k_reduce<<<64, 256, 0, stream>>>(partials, bnacc, NBLK);
  k_head<<<(N_EDGES + 255) / 256, 256, 0, stream>>>(ea1z, bnacc, bn_g, bn_b,
                                                    fm_w2, fm_b2, out);
}